// Round 1
// baseline (960.020 us; speedup 1.0000x reference)
//
#include <hip/hip_runtime.h>
#include <math.h>

#define Bb 4
#define Nn 2048
#define Dd 256
#define Hh 8
#define DHh 32
#define MLPH 1024
#define Ee 262144
#define BNr 8192

__device__ __forceinline__ float gelu_f(float x){
  return 0.5f * x * (1.0f + erff(x * 0.70710678118654752f));
}

// ---------------- edge-index dtype detection ----------------
// If edge_index was staged as int64, every odd int32 (high word) is 0.
// If staged as int32, odd entries are random node ids in [0,8192) -> ~surely nonzero.
__global__ void detect_kernel(const int* __restrict__ ei, int* flag){
  __shared__ int nz;
  if (threadIdx.x == 0) nz = 0;
  __syncthreads();
  int any = 0;
  for (int i = threadIdx.x; i < 2048; i += 256)
    if (ei[2*i + 1] != 0) any = 1;
  if (any) atomicOr(&nz, 1);
  __syncthreads();
  if (threadIdx.x == 0) *flag = nz ? 0 : 1;  // 1 => int64 layout
}

__global__ void count_kernel(const int* __restrict__ ei, const int* __restrict__ flag,
                             int* cnt_row, int* cnt_col){
  int e = blockIdx.x * 256 + threadIdx.x;
  if (e >= Ee) return;
  int m = *flag;
  int r = m ? ei[2*e]          : ei[e];
  int c = m ? ei[2*(Ee + e)]   : ei[Ee + e];
  atomicAdd(&cnt_row[r], 1);
  atomicAdd(&cnt_col[c], 1);
}

// exclusive prefix sum of 8192 counts, single block
__global__ void scan_kernel(const int* __restrict__ cnt, int* start, int* cursor){
  __shared__ int part[256];
  int t = threadIdx.x;
  int s = 0;
  for (int i = 0; i < 32; i++) s += cnt[t*32 + i];
  part[t] = s;
  __syncthreads();
  if (t == 0){
    int run = 0;
    for (int i = 0; i < 256; i++){ int tmp = part[i]; part[i] = run; run += tmp; }
    start[BNr] = run;
  }
  __syncthreads();
  int base = part[t];
  for (int i = 0; i < 32; i++){
    start[t*32 + i]  = base;
    cursor[t*32 + i] = base;
    base += cnt[t*32 + i];
  }
}

__global__ void dis_kernel(const int* __restrict__ cnt_row, float* dis){
  int i = blockIdx.x * 256 + threadIdx.x;
  if (i < BNr){
    int d = cnt_row[i];
    dis[i] = d > 0 ? 1.0f / sqrtf((float)d) : 0.0f;
  }
}

__global__ void fill_kernel(const int* __restrict__ ei, const int* __restrict__ flag,
                            int* cursor, int* bucket){
  int e = blockIdx.x * 256 + threadIdx.x;
  if (e >= Ee) return;
  int m = *flag;
  int c = m ? ei[2*(Ee + e)] : ei[Ee + e];
  int p = atomicAdd(&cursor[c], 1);
  bucket[p] = e;
}

// gather incoming edges per node, add residual + gc_b, LayerNorm
__global__ __launch_bounds__(256) void gather_ln_kernel(
    const float* __restrict__ xt, const int* __restrict__ ei, const int* __restrict__ flag,
    const int* __restrict__ start, const int* __restrict__ bucket,
    const float* __restrict__ dis, const float* __restrict__ x,
    const float* __restrict__ gc_b, const float* __restrict__ gamma,
    const float* __restrict__ beta, float* __restrict__ out){
  int v = blockIdx.x, t = threadIdx.x;
  int m = *flag;
  int s0 = start[v], s1 = start[v+1];
  float dv = dis[v];
  float acc = 0.f;
  for (int ii = s0; ii < s1; ii++){
    int e = bucket[ii];                    // uniform across block -> broadcast
    int r = m ? ei[2*e] : ei[e];
    float nrm = dv * dis[r];
    acc += nrm * xt[(size_t)r*Dd + t];     // coalesced row read
  }
  float val = x[(size_t)v*Dd + t] + acc + gc_b[t];

  float s = val;
  #pragma unroll
  for (int o = 32; o > 0; o >>= 1) s += __shfl_xor(s, o);
  __shared__ float wsum[4], wsum2[4];
  int wid = t >> 6, lane = t & 63;
  if (lane == 0) wsum[wid] = s;
  __syncthreads();
  float mu = (wsum[0]+wsum[1]+wsum[2]+wsum[3]) * (1.0f/Dd);
  float dvl = val - mu;
  float s2 = dvl*dvl;
  #pragma unroll
  for (int o = 32; o > 0; o >>= 1) s2 += __shfl_xor(s2, o);
  if (lane == 0) wsum2[wid] = s2;
  __syncthreads();
  float var = (wsum2[0]+wsum2[1]+wsum2[2]+wsum2[3]) * (1.0f/Dd);
  out[(size_t)v*Dd + t] = dvl * rsqrtf(var + 1e-5f) * gamma[t] + beta[t];
}

__global__ __launch_bounds__(256) void add_ln_kernel(
    const float* __restrict__ a, const float* __restrict__ b,
    const float* __restrict__ gamma, const float* __restrict__ beta,
    float* __restrict__ out){
  int row = blockIdx.x, t = threadIdx.x;
  size_t off = (size_t)row*Dd + t;
  float val = a[off] + b[off];

  float s = val;
  #pragma unroll
  for (int o = 32; o > 0; o >>= 1) s += __shfl_xor(s, o);
  __shared__ float wsum[4], wsum2[4];
  int wid = t >> 6, lane = t & 63;
  if (lane == 0) wsum[wid] = s;
  __syncthreads();
  float mu = (wsum[0]+wsum[1]+wsum[2]+wsum[3]) * (1.0f/Dd);
  float dvl = val - mu;
  float s2 = dvl*dvl;
  #pragma unroll
  for (int o = 32; o > 0; o >>= 1) s2 += __shfl_xor(s2, o);
  if (lane == 0) wsum2[wid] = s2;
  __syncthreads();
  float var = (wsum2[0]+wsum2[1]+wsum2[2]+wsum2[3]) * (1.0f/Dd);
  out[off] = dvl * rsqrtf(var + 1e-5f) * gamma[t] + beta[t];
}

// generic fp32 GEMM: C[M,Nc] = A[M,K] @ W[K,Nc] (+bias) (+gelu)
__global__ __launch_bounds__(256) void gemm_kernel(
    const float* __restrict__ A, const float* __restrict__ W,
    const float* __restrict__ bias, float* __restrict__ C,
    int M, int K, int Nc, int act){
  __shared__ float As[16][68];  // [k][m], padded
  __shared__ float Ws[16][68];  // [k][n], padded
  int t = threadIdx.x;
  int tx = t & 15, ty = t >> 4;
  int n0 = blockIdx.x * 64, m0 = blockIdx.y * 64;
  float acc[4][4] = {};
  for (int k0 = 0; k0 < K; k0 += 16){
    {
      int r = t >> 2, cc = (t & 3) * 4;
      float4 av = *(const float4*)&A[(size_t)(m0 + r)*K + k0 + cc];
      As[cc+0][r] = av.x; As[cc+1][r] = av.y; As[cc+2][r] = av.z; As[cc+3][r] = av.w;
      int kr = t >> 4, nc = (t & 15) * 4;
      float4 wv = *(const float4*)&W[(size_t)(k0 + kr)*Nc + n0 + nc];
      *(float4*)&Ws[kr][nc] = wv;
    }
    __syncthreads();
    #pragma unroll
    for (int kk = 0; kk < 16; kk++){
      float a4[4], w4[4];
      *(float4*)a4 = *(const float4*)&As[kk][ty*4];
      *(float4*)w4 = *(const float4*)&Ws[kk][tx*4];
      #pragma unroll
      for (int i = 0; i < 4; i++)
        #pragma unroll
        for (int jj = 0; jj < 4; jj++)
          acc[i][jj] += a4[i] * w4[jj];
    }
    __syncthreads();
  }
  #pragma unroll
  for (int i = 0; i < 4; i++){
    int mrow = m0 + ty*4 + i;
    float4 o;
    float* op = (float*)&o;
    #pragma unroll
    for (int jj = 0; jj < 4; jj++){
      int ncol = n0 + tx*4 + jj;
      float vsum = acc[i][jj] + (bias ? bias[ncol] : 0.f);
      if (act == 1) vsum = gelu_f(vsum);
      op[jj] = vsum;
    }
    *(float4*)&C[(size_t)mrow*Nc + n0 + tx*4] = o;
  }
}

// flash-style fp32 attention: block = (b, h, 32 q rows), chunks of 32 keys
__global__ __launch_bounds__(256) void attn_kernel(
    const float* __restrict__ Q, const float* __restrict__ K,
    const float* __restrict__ V, float* __restrict__ O){
  __shared__ float Qs[32][36];
  __shared__ float Ks[32][36];
  __shared__ float Vs[32][36];
  __shared__ float Ps[32][36];
  int blk = blockIdx.x;
  int qb = blk & 63;          // N/32 = 64 q-blocks
  int bh = blk >> 6;
  int h = bh & 7, b = bh >> 3;
  size_t base = ((size_t)b * Nn) * Dd + (size_t)h * DHh;
  int t = threadIdx.x;
  int i = t >> 3, j = t & 7;  // row i (0..31), 8 threads per row
  int qrow = qb * 32;
  {
    int r = t >> 3, c0 = (t & 7) * 4;
    *(float4*)&Qs[r][c0] = *(const float4*)&Q[base + (size_t)(qrow + r)*Dd + c0];
  }
  __syncthreads();
  float qreg[32];
  #pragma unroll
  for (int d = 0; d < 32; d++) qreg[d] = Qs[i][d];

  float m = -INFINITY, l = 0.f;
  float4 acc = make_float4(0.f, 0.f, 0.f, 0.f);
  const float scale = 0.17677669529663687f;  // 1/sqrt(32)

  for (int k0 = 0; k0 < Nn; k0 += 32){
    __syncthreads();  // protect Ks/Vs/Ps from previous iteration
    {
      int r = t >> 3, c0 = (t & 7) * 4;
      *(float4*)&Ks[r][c0] = *(const float4*)&K[base + (size_t)(k0 + r)*Dd + c0];
      *(float4*)&Vs[r][c0] = *(const float4*)&V[base + (size_t)(k0 + r)*Dd + c0];
    }
    __syncthreads();
    float s4[4] = {0.f, 0.f, 0.f, 0.f};
    #pragma unroll
    for (int d0 = 0; d0 < 32; d0 += 4){
      #pragma unroll
      for (int kk = 0; kk < 4; kk++){
        float4 k4 = *(const float4*)&Ks[j*4 + kk][d0];
        s4[kk] += qreg[d0]*k4.x + qreg[d0+1]*k4.y + qreg[d0+2]*k4.z + qreg[d0+3]*k4.w;
      }
    }
    #pragma unroll
    for (int kk = 0; kk < 4; kk++) s4[kk] *= scale;
    float mx = fmaxf(fmaxf(s4[0], s4[1]), fmaxf(s4[2], s4[3]));
    #pragma unroll
    for (int o = 1; o < 8; o <<= 1) mx = fmaxf(mx, __shfl_xor(mx, o));
    float M = fmaxf(m, mx);
    float corr = __expf(m - M);  // 0 on first chunk (m=-inf)
    float p0 = __expf(s4[0]-M), p1 = __expf(s4[1]-M),
          p2 = __expf(s4[2]-M), p3 = __expf(s4[3]-M);
    float ps = p0 + p1 + p2 + p3;
    #pragma unroll
    for (int o = 1; o < 8; o <<= 1) ps += __shfl_xor(ps, o);
    l = l * corr + ps;
    m = M;
    acc.x *= corr; acc.y *= corr; acc.z *= corr; acc.w *= corr;
    *(float4*)&Ps[i][j*4] = make_float4(p0, p1, p2, p3);
    __syncthreads();
    #pragma unroll
    for (int k = 0; k < 32; k++){
      float pk = Ps[i][k];
      float4 v4 = *(const float4*)&Vs[k][j*4];
      acc.x += pk * v4.x; acc.y += pk * v4.y;
      acc.z += pk * v4.z; acc.w += pk * v4.w;
    }
  }
  float invl = 1.0f / l;
  acc.x *= invl; acc.y *= invl; acc.z *= invl; acc.w *= invl;
  *(float4*)&O[base + (size_t)(qrow + i)*Dd + j*4] = acc;
}

extern "C" void kernel_launch(void* const* d_in, const int* in_sizes, int n_in,
                              void* d_out, int out_size, void* d_ws, size_t ws_size,
                              hipStream_t stream){
  const float* x      = (const float*)d_in[0];
  const int*   ei     = (const int*)d_in[1];
  const float* gc_w   = (const float*)d_in[2];
  const float* gc_b   = (const float*)d_in[3];
  const float* g_gamma= (const float*)d_in[4];
  const float* g_beta = (const float*)d_in[5];
  const float* wq = (const float*)d_in[6];  const float* bq = (const float*)d_in[7];
  const float* wk = (const float*)d_in[8];  const float* bk = (const float*)d_in[9];
  const float* wv = (const float*)d_in[10]; const float* bv = (const float*)d_in[11];
  const float* wo = (const float*)d_in[12]; const float* bo = (const float*)d_in[13];
  const float* a_gamma = (const float*)d_in[14]; const float* a_beta = (const float*)d_in[15];
  const float* w1 = (const float*)d_in[16]; const float* b1 = (const float*)d_in[17];
  const float* w2 = (const float*)d_in[18]; const float* b2 = (const float*)d_in[19];
  const float* m_gamma = (const float*)d_in[20]; const float* m_beta = (const float*)d_in[21];
  float* out = (float*)d_out;

  const size_t S = (size_t)BNr * Dd;  // 2,097,152 floats per [BN,D] buffer
  float* F  = (float*)d_ws;
  float* XT = F;            // slot 0 (reused as PROJ)
  float* X1 = F + 1*S;      // slot 1
  float* Qb = F + 2*S;      // slot 2 (reused as X2)
  float* Kb = F + 3*S;      // slot 3 (reused as MO)
  float* Vb = F + 4*S;      // slot 4
  float* AO = F + 5*S;      // slot 5
  float* Hb = F + 6*S;      // slots 6..9 (BN x 1024)
  float* PROJ = XT;
  float* X2   = Qb;
  float* MO   = Kb;

  int* I       = (int*)(F + 10*S);
  int* cnt_row = I;                 // 8192
  int* cnt_col = I + 8192;          // 8192
  int* startA  = I + 16384;         // 8193
  int* cursor  = I + 24704;         // 8192
  int* bucket  = I + 33024;         // 262144
  float* dis   = (float*)(I + 33024 + Ee);  // 8192
  int* flag    = (int*)(dis + 8192);

  hipMemsetAsync(cnt_row, 0, 2 * 8192 * sizeof(int), stream);

  detect_kernel<<<1, 256, 0, stream>>>(ei, flag);
  count_kernel<<<Ee/256, 256, 0, stream>>>(ei, flag, cnt_row, cnt_col);
  scan_kernel<<<1, 256, 0, stream>>>(cnt_col, startA, cursor);
  dis_kernel<<<32, 256, 0, stream>>>(cnt_row, dis);
  fill_kernel<<<Ee/256, 256, 0, stream>>>(ei, flag, cursor, bucket);

  // xt = x @ gc_w
  gemm_kernel<<<dim3(Dd/64, BNr/64), 256, 0, stream>>>(x, gc_w, nullptr, XT, BNr, Dd, Dd, 0);
  // GraphConv gather + residual + LN1 -> X1
  gather_ln_kernel<<<BNr, 256, 0, stream>>>(XT, ei, flag, startA, bucket, dis,
                                            x, gc_b, g_gamma, g_beta, X1);
  // QKV
  gemm_kernel<<<dim3(Dd/64, BNr/64), 256, 0, stream>>>(X1, wq, bq, Qb, BNr, Dd, Dd, 0);
  gemm_kernel<<<dim3(Dd/64, BNr/64), 256, 0, stream>>>(X1, wk, bk, Kb, BNr, Dd, Dd, 0);
  gemm_kernel<<<dim3(Dd/64, BNr/64), 256, 0, stream>>>(X1, wv, bv, Vb, BNr, Dd, Dd, 0);
  // attention
  attn_kernel<<<Bb*Hh*(Nn/32), 256, 0, stream>>>(Qb, Kb, Vb, AO);
  // out proj + LN2
  gemm_kernel<<<dim3(Dd/64, BNr/64), 256, 0, stream>>>(AO, wo, bo, PROJ, BNr, Dd, Dd, 0);
  add_ln_kernel<<<BNr, 256, 0, stream>>>(X1, PROJ, a_gamma, a_beta, X2);
  // MLP
  gemm_kernel<<<dim3(MLPH/64, BNr/64), 256, 0, stream>>>(X2, w1, b1, Hb, BNr, Dd, MLPH, 1);
  gemm_kernel<<<dim3(Dd/64, BNr/64), 256, 0, stream>>>(Hb, w2, b2, MO, BNr, MLPH, Dd, 0);
  add_ln_kernel<<<BNr, 256, 0, stream>>>(X2, MO, m_gamma, m_beta, out);
}

// Round 2
// 483.869 us; speedup vs baseline: 1.9840x; 1.9840x over previous
//
#include <hip/hip_runtime.h>
#include <math.h>

#define Bb 4
#define Nn 2048
#define Dd 256
#define Hh 8
#define DHh 32
#define MLPH 1024
#define Ee 262144
#define BNr 8192

typedef __attribute__((ext_vector_type(8))) short bf8;   // 8 bf16 in 4 VGPRs
typedef __attribute__((ext_vector_type(4))) float f4;

__device__ __forceinline__ float gelu_f(float x){
  return 0.5f * x * (1.0f + erff(x * 0.70710678118654752f));
}

__device__ __forceinline__ ushort f2bf(float f){
  union { float f; unsigned u; } v; v.f = f;
  unsigned r = v.u + 0x7fffu + ((v.u >> 16) & 1u);   // RNE
  return (ushort)(r >> 16);
}

// ---------------- edge-index dtype detection ----------------
__global__ void detect_kernel(const int* __restrict__ ei, int* flag){
  __shared__ int nz;
  if (threadIdx.x == 0) nz = 0;
  __syncthreads();
  int any = 0;
  for (int i = threadIdx.x; i < 2048; i += 256)
    if (ei[2*i + 1] != 0) any = 1;
  if (any) atomicOr(&nz, 1);
  __syncthreads();
  if (threadIdx.x == 0) *flag = nz ? 0 : 1;  // 1 => int64 layout
}

__global__ void count_kernel(const int* __restrict__ ei, const int* __restrict__ flag,
                             int* cnt_row, int* cnt_col){
  int e = blockIdx.x * 256 + threadIdx.x;
  if (e >= Ee) return;
  int m = *flag;
  int r = m ? ei[2*e]          : ei[e];
  int c = m ? ei[2*(Ee + e)]   : ei[Ee + e];
  atomicAdd(&cnt_row[r], 1);
  atomicAdd(&cnt_col[c], 1);
}

__global__ void scan_kernel(const int* __restrict__ cnt, int* start, int* cursor){
  __shared__ int part[256];
  int t = threadIdx.x;
  int s = 0;
  for (int i = 0; i < 32; i++) s += cnt[t*32 + i];
  part[t] = s;
  __syncthreads();
  if (t == 0){
    int run = 0;
    for (int i = 0; i < 256; i++){ int tmp = part[i]; part[i] = run; run += tmp; }
    start[BNr] = run;
  }
  __syncthreads();
  int base = part[t];
  for (int i = 0; i < 32; i++){
    start[t*32 + i]  = base;
    cursor[t*32 + i] = base;
    base += cnt[t*32 + i];
  }
}

__global__ void dis_kernel(const int* __restrict__ cnt_row, float* dis){
  int i = blockIdx.x * 256 + threadIdx.x;
  if (i < BNr){
    int d = cnt_row[i];
    dis[i] = d > 0 ? 1.0f / sqrtf((float)d) : 0.0f;
  }
}

__global__ void fill_kernel(const int* __restrict__ ei, const int* __restrict__ flag,
                            int* cursor, int* bucket){
  int e = blockIdx.x * 256 + threadIdx.x;
  if (e >= Ee) return;
  int m = *flag;
  int c = m ? ei[2*(Ee + e)] : ei[Ee + e];
  int p = atomicAdd(&cursor[c], 1);
  bucket[p] = e;
}

// ---------------- converts ----------------
__global__ void conv_kernel(const float* __restrict__ src, ushort* __restrict__ dst, int n4){
  int i = blockIdx.x * 256 + threadIdx.x;
  if (i < n4){
    float4 v = ((const float4*)src)[i];
    ushort4 o;
    o.x = f2bf(v.x); o.y = f2bf(v.y); o.z = f2bf(v.z); o.w = f2bf(v.w);
    ((ushort4*)dst)[i] = o;
  }
}

// transpose-convert fp32 [R][C] -> bf16 [C][R]
__device__ __forceinline__ void tconv_body(const float* src, ushort* dst, int R, int C){
  __shared__ float tile[32][33];
  int c0 = blockIdx.x * 32, r0 = blockIdx.y * 32;
  int tx = threadIdx.x & 31, ty = threadIdx.x >> 5;  // 256 threads: ty 0..7
  for (int i = ty; i < 32; i += 8)
    tile[i][tx] = src[(size_t)(r0 + i) * C + c0 + tx];
  __syncthreads();
  for (int i = ty; i < 32; i += 8)
    dst[(size_t)(c0 + i) * R + r0 + tx] = f2bf(tile[tx][i]);
}

__global__ void tconv_kernel(const float* __restrict__ src, ushort* __restrict__ dst, int R, int C){
  tconv_body(src, dst, R, C);
}

__global__ void tconv5_kernel(const float* s0, const float* s1, const float* s2,
                              const float* s3, const float* s4,
                              ushort* d0, ushort* d1, ushort* d2, ushort* d3, ushort* d4){
  const float* s; ushort* d;
  switch (blockIdx.z){
    case 0: s = s0; d = d0; break;
    case 1: s = s1; d = d1; break;
    case 2: s = s2; d = d2; break;
    case 3: s = s3; d = d3; break;
    default: s = s4; d = d4; break;
  }
  tconv_body(s, d, 256, 256);
}

// ---------------- GraphConv gather + residual + LN1 ----------------
__global__ __launch_bounds__(256) void gather_ln_kernel(
    const float* __restrict__ xt, const int* __restrict__ ei, const int* __restrict__ flag,
    const int* __restrict__ start, const int* __restrict__ bucket,
    const float* __restrict__ dis, const float* __restrict__ x,
    const float* __restrict__ gc_b, const float* __restrict__ gamma,
    const float* __restrict__ beta, float* __restrict__ out, ushort* __restrict__ outb){
  int v = blockIdx.x, t = threadIdx.x;
  int m = *flag;
  int s0 = start[v], s1 = start[v+1];
  float dv = dis[v];
  float acc = 0.f;
  for (int ii = s0; ii < s1; ii++){
    int e = bucket[ii];
    int r = m ? ei[2*e] : ei[e];
    float nrm = dv * dis[r];
    acc += nrm * xt[(size_t)r*Dd + t];
  }
  float val = x[(size_t)v*Dd + t] + acc + gc_b[t];

  float s = val;
  #pragma unroll
  for (int o = 32; o > 0; o >>= 1) s += __shfl_xor(s, o);
  __shared__ float wsum[4], wsum2[4];
  int wid = t >> 6, lane = t & 63;
  if (lane == 0) wsum[wid] = s;
  __syncthreads();
  float mu = (wsum[0]+wsum[1]+wsum[2]+wsum[3]) * (1.0f/Dd);
  float dvl = val - mu;
  float s2 = dvl*dvl;
  #pragma unroll
  for (int o = 32; o > 0; o >>= 1) s2 += __shfl_xor(s2, o);
  if (lane == 0) wsum2[wid] = s2;
  __syncthreads();
  float var = (wsum2[0]+wsum2[1]+wsum2[2]+wsum2[3]) * (1.0f/Dd);
  float res = dvl * rsqrtf(var + 1e-5f) * gamma[t] + beta[t];
  out[(size_t)v*Dd + t] = res;
  outb[(size_t)v*Dd + t] = f2bf(res);
}

__global__ __launch_bounds__(256) void add_ln_kernel(
    const float* __restrict__ a, const float* __restrict__ b,
    const float* __restrict__ gamma, const float* __restrict__ beta,
    float* __restrict__ out, ushort* __restrict__ outb){
  int row = blockIdx.x, t = threadIdx.x;
  size_t off = (size_t)row*Dd + t;
  float val = a[off] + b[off];

  float s = val;
  #pragma unroll
  for (int o = 32; o > 0; o >>= 1) s += __shfl_xor(s, o);
  __shared__ float wsum[4], wsum2[4];
  int wid = t >> 6, lane = t & 63;
  if (lane == 0) wsum[wid] = s;
  __syncthreads();
  float mu = (wsum[0]+wsum[1]+wsum[2]+wsum[3]) * (1.0f/Dd);
  float dvl = val - mu;
  float s2 = dvl*dvl;
  #pragma unroll
  for (int o = 32; o > 0; o >>= 1) s2 += __shfl_xor(s2, o);
  if (lane == 0) wsum2[wid] = s2;
  __syncthreads();
  float var = (wsum2[0]+wsum2[1]+wsum2[2]+wsum2[3]) * (1.0f/Dd);
  float res = dvl * rsqrtf(var + 1e-5f) * gamma[t] + beta[t];
  out[off] = res;
  if (outb) outb[off] = f2bf(res);
}

// ---------------- bf16 MFMA GEMM ----------------
// C[M,N] = A[M,K] @ W[K,N], with Bt = W^T given as bf16 [N,K].
// tile 128x64, BK=32, 256 threads = 4 waves in 2x2 (wave: 64x32 out).
#define LDA_S 56   // LDS row stride in elems: 112B, multiple of 16B

template<int OB, int ACT>
__global__ __launch_bounds__(256,2) void gemm_bf16(
    const ushort* __restrict__ A, const ushort* __restrict__ Bt,
    const float* __restrict__ bias, float* __restrict__ Cf, ushort* __restrict__ Cb,
    int M, int K, int N){
  __shared__ ushort As[2][128*LDA_S];
  __shared__ ushort Bs[2][64*LDA_S];
  int t = threadIdx.x;
  int lane = t & 63, wid = t >> 6;
  int wm = wid >> 1, wn = wid & 1;
  int l15 = lane & 15, lg = lane >> 4;
  int m0 = blockIdx.y * 128, n0 = blockIdx.x * 64;

  int sr = t >> 2;            // 0..63
  int sk = (t & 3) * 8;       // 0,8,16,24
  const ushort* Ag1 = A  + (size_t)(m0 + sr) * K + sk;
  const ushort* Ag2 = A  + (size_t)(m0 + 64 + sr) * K + sk;
  const ushort* Bg  = Bt + (size_t)(n0 + sr) * K + sk;

  int nsteps = K / 32;
  bf8 ra1 = *(const bf8*)Ag1;
  bf8 ra2 = *(const bf8*)Ag2;
  bf8 rb  = *(const bf8*)Bg;
  *(bf8*)&As[0][sr*LDA_S + sk]        = ra1;
  *(bf8*)&As[0][(64+sr)*LDA_S + sk]   = ra2;
  *(bf8*)&Bs[0][sr*LDA_S + sk]        = rb;
  __syncthreads();

  f4 acc[4][2] = {};
  for (int ks = 0; ks < nsteps; ks++){
    int cur = ks & 1;
    if (ks + 1 < nsteps){
      ra1 = *(const bf8*)(Ag1 + (ks+1)*32);
      ra2 = *(const bf8*)(Ag2 + (ks+1)*32);
      rb  = *(const bf8*)(Bg  + (ks+1)*32);
    }
    bf8 af[4], bfr[2];
    #pragma unroll
    for (int mf = 0; mf < 4; mf++)
      af[mf] = *(bf8*)&As[cur][(wm*64 + mf*16 + l15)*LDA_S + lg*8];
    #pragma unroll
    for (int nf = 0; nf < 2; nf++)
      bfr[nf] = *(bf8*)&Bs[cur][(wn*32 + nf*16 + l15)*LDA_S + lg*8];
    #pragma unroll
    for (int mf = 0; mf < 4; mf++)
      #pragma unroll
      for (int nf = 0; nf < 2; nf++)
        acc[mf][nf] = __builtin_amdgcn_mfma_f32_16x16x32_bf16(af[mf], bfr[nf], acc[mf][nf], 0, 0, 0);
    __syncthreads();
    if (ks + 1 < nsteps){
      int nxt = cur ^ 1;
      *(bf8*)&As[nxt][sr*LDA_S + sk]      = ra1;
      *(bf8*)&As[nxt][(64+sr)*LDA_S + sk] = ra2;
      *(bf8*)&Bs[nxt][sr*LDA_S + sk]      = rb;
      __syncthreads();
    }
  }

  #pragma unroll
  for (int mf = 0; mf < 4; mf++){
    int row = m0 + wm*64 + mf*16 + lg*4;
    #pragma unroll
    for (int nf = 0; nf < 2; nf++){
      int col = n0 + wn*32 + nf*16 + l15;
      float bv = bias ? bias[col] : 0.f;
      #pragma unroll
      for (int r = 0; r < 4; r++){
        float v = acc[mf][nf][r] + bv;
        if (ACT) v = gelu_f(v);
        if (OB) Cb[(size_t)(row + r) * N + col] = f2bf(v);
        else    Cf[(size_t)(row + r) * N + col] = v;
      }
    }
  }
}

// ---------------- MFMA flash attention ----------------
// bf16 Q,K,V [B*N][D]; per block: (b,h) + 128 q rows; 4 waves x 32 q rows.
#define PL_S 72    // P_lds row stride (elems): 144B, mult of 16
#define VT_S 104   // Vt row stride: 208B, mult of 16

__global__ __launch_bounds__(256,2) void attn_mfma_kernel(
    const ushort* __restrict__ Q, const ushort* __restrict__ K,
    const ushort* __restrict__ V, ushort* __restrict__ O){
  __shared__ ushort Pl[128 * PL_S];
  __shared__ ushort Vt[32 * VT_S];
  int bh = blockIdx.x >> 4, qb = blockIdx.x & 15;
  int b = bh >> 3, h = bh & 7;
  size_t base = ((size_t)b * Nn) * Dd + (size_t)h * DHh;
  int t = threadIdx.x;
  int lane = t & 63, wid = t >> 6;
  int l15 = lane & 15, lg = lane >> 4;
  int q0 = qb * 128 + wid * 32;
  const float scale = 0.17677669529663687f;  // 1/sqrt(32)

  // Q A-frags in regs (2 x 16 q-rows)
  bf8 qf[2];
  #pragma unroll
  for (int mf = 0; mf < 2; mf++)
    qf[mf] = *(const bf8*)&Q[base + (size_t)(q0 + mf*16 + l15) * Dd + lg*8];

  float m_st[2][4], l_st[2][4];
  f4 oacc[2][2] = {};
  #pragma unroll
  for (int mf = 0; mf < 2; mf++)
    #pragma unroll
    for (int r = 0; r < 4; r++){ m_st[mf][r] = -1e30f; l_st[mf][r] = 0.f; }

  // Vt staging mapping: thread -> (key, dh0)
  int vkey = t >> 2;          // 0..63
  int vdh0 = (t & 3) * 8;     // 0,8,16,24

  for (int kc = 0; kc < Nn/64; kc++){
    int k0 = kc * 64;
    __syncthreads();   // Vt / Pl free (prev chunk's PV reads done)

    // stage V^T chunk: Vt[dh][key]
    {
      bf8 v8 = *(const bf8*)&V[base + (size_t)(k0 + vkey) * Dd + vdh0];
      #pragma unroll
      for (int i = 0; i < 8; i++)
        Vt[(vdh0 + i) * VT_S + vkey] = (ushort)v8[i];
    }

    // S = Q K^T (K-frags direct from global; L2-resident)
    f4 s[2][4] = {};
    #pragma unroll
    for (int kt = 0; kt < 4; kt++){
      bf8 kf = *(const bf8*)&K[base + (size_t)(k0 + kt*16 + l15) * Dd + lg*8];
      #pragma unroll
      for (int mf = 0; mf < 2; mf++)
        s[mf][kt] = __builtin_amdgcn_mfma_f32_16x16x32_bf16(qf[mf], kf, s[mf][kt], 0, 0, 0);
    }

    // online softmax per (mf, reg): row = q, cols spread over 16 lanes x 4 ktiles
    #pragma unroll
    for (int mf = 0; mf < 2; mf++){
      #pragma unroll
      for (int r = 0; r < 4; r++){
        float sc0 = s[mf][0][r] * scale;
        float sc1 = s[mf][1][r] * scale;
        float sc2 = s[mf][2][r] * scale;
        float sc3 = s[mf][3][r] * scale;
        float mx = fmaxf(fmaxf(sc0, sc1), fmaxf(sc2, sc3));
        #pragma unroll
        for (int o = 1; o < 16; o <<= 1) mx = fmaxf(mx, __shfl_xor(mx, o));
        float Mn = fmaxf(m_st[mf][r], mx);
        float corr = __expf(m_st[mf][r] - Mn);
        float p0 = __expf(sc0 - Mn), p1 = __expf(sc1 - Mn);
        float p2 = __expf(sc2 - Mn), p3 = __expf(sc3 - Mn);
        float ps = p0 + p1 + p2 + p3;
        #pragma unroll
        for (int o = 1; o < 16; o <<= 1) ps += __shfl_xor(ps, o);
        l_st[mf][r] = l_st[mf][r] * corr + ps;
        m_st[mf][r] = Mn;
        oacc[mf][0][r] *= corr;
        oacc[mf][1][r] *= corr;
        int prow = (wid*32 + mf*16 + lg*4 + r) * PL_S;
        Pl[prow + 0*16 + l15] = f2bf(p0);
        Pl[prow + 1*16 + l15] = f2bf(p1);
        Pl[prow + 2*16 + l15] = f2bf(p2);
        Pl[prow + 3*16 + l15] = f2bf(p3);
      }
    }
    __syncthreads();   // Vt staged + P written

    // PV: O += P[128x64] * V[64x32]
    bf8 vf[2][2];
    #pragma unroll
    for (int ksb = 0; ksb < 2; ksb++)
      #pragma unroll
      for (int nt = 0; nt < 2; nt++)
        vf[ksb][nt] = *(bf8*)&Vt[(nt*16 + l15) * VT_S + ksb*32 + lg*8];
    #pragma unroll
    for (int mf = 0; mf < 2; mf++){
      #pragma unroll
      for (int ksb = 0; ksb < 2; ksb++){
        bf8 pf = *(bf8*)&Pl[(wid*32 + mf*16 + l15) * PL_S + ksb*32 + lg*8];
        #pragma unroll
        for (int nt = 0; nt < 2; nt++)
          oacc[mf][nt] = __builtin_amdgcn_mfma_f32_16x16x32_bf16(pf, vf[ksb][nt], oacc[mf][nt], 0, 0, 0);
      }
    }
  }

  // write O (bf16)
  #pragma unroll
  for (int mf = 0; mf < 2; mf++){
    #pragma unroll
    for (int r = 0; r < 4; r++){
      float invl = 1.0f / l_st[mf][r];
      int row = q0 + mf*16 + lg*4 + r;
      #pragma unroll
      for (int nt = 0; nt < 2; nt++)
        O[base + (size_t)row * Dd + nt*16 + l15] = f2bf(oacc[mf][nt][r] * invl);
    }
  }
}

extern "C" void kernel_launch(void* const* d_in, const int* in_sizes, int n_in,
                              void* d_out, int out_size, void* d_ws, size_t ws_size,
                              hipStream_t stream){
  const float* x      = (const float*)d_in[0];
  const int*   ei     = (const int*)d_in[1];
  const float* gc_w   = (const float*)d_in[2];
  const float* gc_b   = (const float*)d_in[3];
  const float* g_gamma= (const float*)d_in[4];
  const float* g_beta = (const float*)d_in[5];
  const float* wq = (const float*)d_in[6];  const float* bq = (const float*)d_in[7];
  const float* wk = (const float*)d_in[8];  const float* bk = (const float*)d_in[9];
  const float* wv = (const float*)d_in[10]; const float* bv = (const float*)d_in[11];
  const float* wo = (const float*)d_in[12]; const float* bo = (const float*)d_in[13];
  const float* a_gamma = (const float*)d_in[14]; const float* a_beta = (const float*)d_in[15];
  const float* w1 = (const float*)d_in[16]; const float* b1 = (const float*)d_in[17];
  const float* w2 = (const float*)d_in[18]; const float* b2 = (const float*)d_in[19];
  const float* m_gamma = (const float*)d_in[20]; const float* m_beta = (const float*)d_in[21];
  float* out = (float*)d_out;

  const size_t S = (size_t)BNr * Dd;   // 2,097,152

  char* p = (char*)d_ws;
  auto alloc = [&](size_t bytes){ char* r = p; p += (bytes + 255) & ~(size_t)255; return r; };

  float* XT   = (float*)alloc(S * 4);       // also PROJ
  float* X1   = (float*)alloc(S * 4);
  float* X2   = (float*)alloc(S * 4);
  float* MO   = (float*)alloc(S * 4);
  ushort* xbf  = (ushort*)alloc(S * 2);
  ushort* X1b  = (ushort*)alloc(S * 2);
  ushort* Qb   = (ushort*)alloc(S * 2);
  ushort* Kb   = (ushort*)alloc(S * 2);
  ushort* Vb   = (ushort*)alloc(S * 2);
  ushort* AOb  = (ushort*)alloc(S * 2);
  ushort* X2b  = (ushort*)alloc(S * 2);
  ushort* Hb   = (ushort*)alloc((size_t)BNr * MLPH * 2);
  ushort* gcwT = (ushort*)alloc(65536 * 2);
  ushort* wqT  = (ushort*)alloc(65536 * 2);
  ushort* wkT  = (ushort*)alloc(65536 * 2);
  ushort* wvT  = (ushort*)alloc(65536 * 2);
  ushort* woT  = (ushort*)alloc(65536 * 2);
  ushort* w1T  = (ushort*)alloc(262144 * 2);
  ushort* w2T  = (ushort*)alloc(262144 * 2);
  int* cnt_row = (int*)alloc(8192 * 4);
  int* cnt_col = (int*)alloc(8192 * 4);
  int* startA  = (int*)alloc(8200 * 4);
  int* cursor  = (int*)alloc(8192 * 4);
  int* bucket  = (int*)alloc(Ee * 4);
  float* dis   = (float*)alloc(8192 * 4);
  int* flag    = (int*)alloc(256);

  float* PROJ = XT;

  hipMemsetAsync(cnt_row, 0, 8192 * sizeof(int), stream);
  hipMemsetAsync(cnt_col, 0, 8192 * sizeof(int), stream);

  // graph prep
  detect_kernel<<<1, 256, 0, stream>>>(ei, flag);
  count_kernel<<<Ee/256, 256, 0, stream>>>(ei, flag, cnt_row, cnt_col);
  scan_kernel<<<1, 256, 0, stream>>>(cnt_col, startA, cursor);
  dis_kernel<<<32, 256, 0, stream>>>(cnt_row, dis);
  fill_kernel<<<Ee/256, 256, 0, stream>>>(ei, flag, cursor, bucket);

  // converts
  conv_kernel<<<(int)(S/4/256), 256, 0, stream>>>(x, xbf, (int)(S/4));
  tconv5_kernel<<<dim3(8,8,5), 256, 0, stream>>>(gc_w, wq, wk, wv, wo, gcwT, wqT, wkT, wvT, woT);
  tconv_kernel<<<dim3(32,8), 256, 0, stream>>>(w1, w1T, 256, 1024);
  tconv_kernel<<<dim3(8,32), 256, 0, stream>>>(w2, w2T, 1024, 256);

  // xt = x @ gc_w  (fp32 out, no bias)
  gemm_bf16<0,0><<<dim3(Dd/64, BNr/128), 256, 0, stream>>>(xbf, gcwT, nullptr, XT, nullptr, BNr, Dd, Dd);
  // GraphConv gather + residual + LN1 -> X1 (fp32 + bf16)
  gather_ln_kernel<<<BNr, 256, 0, stream>>>(XT, ei, flag, startA, bucket, dis,
                                            x, gc_b, g_gamma, g_beta, X1, X1b);
  // QKV (bf16 out)
  gemm_bf16<1,0><<<dim3(Dd/64, BNr/128), 256, 0, stream>>>(X1b, wqT, bq, nullptr, Qb, BNr, Dd, Dd);
  gemm_bf16<1,0><<<dim3(Dd/64, BNr/128), 256, 0, stream>>>(X1b, wkT, bk, nullptr, Kb, BNr, Dd, Dd);
  gemm_bf16<1,0><<<dim3(Dd/64, BNr/128), 256, 0, stream>>>(X1b, wvT, bv, nullptr, Vb, BNr, Dd, Dd);
  // attention
  attn_mfma_kernel<<<Bb*Hh*16, 256, 0, stream>>>(Qb, Kb, Vb, AOb);
  // out proj (fp32) + LN2
  gemm_bf16<0,0><<<dim3(Dd/64, BNr/128), 256, 0, stream>>>(AOb, woT, bo, PROJ, nullptr, BNr, Dd, Dd);
  add_ln_kernel<<<BNr, 256, 0, stream>>>(X1, PROJ, a_gamma, a_beta, X2, X2b);
  // MLP
  gemm_bf16<1,1><<<dim3(MLPH/64, BNr/128), 256, 0, stream>>>(X2b, w1T, b1, nullptr, Hb, BNr, Dd, MLPH);
  gemm_bf16<0,0><<<dim3(Dd/64, BNr/128), 256, 0, stream>>>(Hb, w2T, b2, MO, nullptr, BNr, MLPH, Dd);
  add_ln_kernel<<<BNr, 256, 0, stream>>>(X2, MO, m_gamma, m_beta, out, nullptr);
}

// Round 3
// 422.463 us; speedup vs baseline: 2.2724x; 1.1454x over previous
//
#include <hip/hip_runtime.h>
#include <math.h>

#define Bb 4
#define Nn 2048
#define Dd 256
#define Hh 8
#define DHh 32
#define MLPH 1024
#define Ee 262144
#define BNr 8192
#define SD 768          // fused QKV row stride
#define PS 88           // P_lds row stride (ushorts) = 176B
#define VS 88           // Vt_lds row stride (ushorts)

typedef __attribute__((ext_vector_type(8))) short bf8;   // 8 bf16 in 4 VGPRs
typedef __attribute__((ext_vector_type(4))) float f4;

__device__ __forceinline__ float gelu_f(float x){
  return 0.5f * x * (1.0f + erff(x * 0.70710678118654752f));
}

__device__ __forceinline__ ushort f2bf(float f){
  union { float f; unsigned u; } v; v.f = f;
  unsigned r = v.u + 0x7fffu + ((v.u >> 16) & 1u);   // RNE
  return (ushort)(r >> 16);
}
__device__ __forceinline__ float bf2f(ushort u){
  return __uint_as_float((unsigned)u << 16);
}

// ---------------- edge-index dtype detection ----------------
__global__ void detect_kernel(const int* __restrict__ ei, int* flag){
  __shared__ int nz;
  if (threadIdx.x == 0) nz = 0;
  __syncthreads();
  int any = 0;
  for (int i = threadIdx.x; i < 2048; i += 256)
    if (ei[2*i + 1] != 0) any = 1;
  if (any) atomicOr(&nz, 1);
  __syncthreads();
  if (threadIdx.x == 0) *flag = nz ? 0 : 1;  // 1 => int64 layout
}

__global__ void count_kernel(const int* __restrict__ ei, const int* __restrict__ flag,
                             int* cnt_row, int* cnt_col){
  int e = blockIdx.x * 256 + threadIdx.x;
  if (e >= Ee) return;
  int m = *flag;
  int r = m ? ei[2*e]          : ei[e];
  int c = m ? ei[2*(Ee + e)]   : ei[Ee + e];
  atomicAdd(&cnt_row[r], 1);
  atomicAdd(&cnt_col[c], 1);
}

__global__ void scan_kernel(const int* __restrict__ cnt, int* start, int* cursor){
  __shared__ int part[256];
  int t = threadIdx.x;
  int s = 0;
  for (int i = 0; i < 32; i++) s += cnt[t*32 + i];
  part[t] = s;
  __syncthreads();
  if (t == 0){
    int run = 0;
    for (int i = 0; i < 256; i++){ int tmp = part[i]; part[i] = run; run += tmp; }
    start[BNr] = run;
  }
  __syncthreads();
  int base = part[t];
  for (int i = 0; i < 32; i++){
    start[t*32 + i]  = base;
    cursor[t*32 + i] = base;
    base += cnt[t*32 + i];
  }
}

__global__ void dis_kernel(const int* __restrict__ cnt_row, float* dis){
  int i = blockIdx.x * 256 + threadIdx.x;
  if (i < BNr){
    int d = cnt_row[i];
    dis[i] = d > 0 ? 1.0f / sqrtf((float)d) : 0.0f;
  }
}

__global__ void fill_kernel(const int* __restrict__ ei, const int* __restrict__ flag,
                            int* cursor, int* bucket){
  int e = blockIdx.x * 256 + threadIdx.x;
  if (e >= Ee) return;
  int m = *flag;
  int c = m ? ei[2*(Ee + e)] : ei[Ee + e];
  int p = atomicAdd(&cursor[c], 1);
  bucket[p] = e;
}

// ---------------- converts ----------------
__global__ void conv_kernel(const float* __restrict__ src, ushort* __restrict__ dst, int n4){
  int i = blockIdx.x * 256 + threadIdx.x;
  if (i < n4){
    float4 v = ((const float4*)src)[i];
    ushort4 o;
    o.x = f2bf(v.x); o.y = f2bf(v.y); o.z = f2bf(v.z); o.w = f2bf(v.w);
    ((ushort4*)dst)[i] = o;
  }
}

// transpose-convert fp32 [R][C] -> bf16 [C][R]
__device__ __forceinline__ void tconv_body(const float* src, ushort* dst, int R, int C){
  __shared__ float tile[32][33];
  int c0 = blockIdx.x * 32, r0 = blockIdx.y * 32;
  int tx = threadIdx.x & 31, ty = threadIdx.x >> 5;
  for (int i = ty; i < 32; i += 8)
    tile[i][tx] = src[(size_t)(r0 + i) * C + c0 + tx];
  __syncthreads();
  for (int i = ty; i < 32; i += 8)
    dst[(size_t)(c0 + i) * R + r0 + tx] = f2bf(tile[tx][i]);
}

__global__ void tconv_kernel(const float* __restrict__ src, ushort* __restrict__ dst, int R, int C){
  tconv_body(src, dst, R, C);
}

__global__ void tconv5_kernel(const float* s0, const float* s1, const float* s2,
                              const float* s3, const float* s4,
                              ushort* d0, ushort* d1, ushort* d2, ushort* d3, ushort* d4){
  const float* s; ushort* d;
  switch (blockIdx.z){
    case 0: s = s0; d = d0; break;
    case 1: s = s1; d = d1; break;
    case 2: s = s2; d = d2; break;
    case 3: s = s3; d = d3; break;
    default: s = s4; d = d4; break;
  }
  tconv_body(s, d, 256, 256);
}

__global__ void bias_cat_kernel(const float* __restrict__ bq, const float* __restrict__ bk,
                                const float* __restrict__ bv, float* __restrict__ o){
  int i = blockIdx.x * 256 + threadIdx.x;
  if (i < 256) o[i] = bq[i];
  else if (i < 512) o[i] = bk[i - 256];
  else if (i < 768) o[i] = bv[i - 512];
}

// V slice of fused QKV -> Vt global [b*H+h][32 dh][2048 n]
__global__ void vt_kernel(const ushort* __restrict__ QKV, ushort* __restrict__ VtG){
  __shared__ ushort tile[32][33];
  int n0 = blockIdx.x * 32, bh = blockIdx.y;
  int b = bh >> 3, h = bh & 7;
  int tx = threadIdx.x & 31, ty = threadIdx.x >> 5;
  for (int i = ty; i < 32; i += 8)
    tile[i][tx] = QKV[(size_t)(b*Nn + n0 + i)*SD + 512 + h*DHh + tx];
  __syncthreads();
  for (int i = ty; i < 32; i += 8)
    VtG[(size_t)bh*DHh*Nn + (size_t)i*Nn + n0 + tx] = tile[tx][i];
}

// ---------------- GraphConv gather (bf16 xt) + residual + LN1 ----------------
__global__ __launch_bounds__(256) void gather_ln_kernel(
    const ushort* __restrict__ xtb, const int* __restrict__ ei, const int* __restrict__ flag,
    const int* __restrict__ start, const int* __restrict__ bucket,
    const float* __restrict__ dis, const float* __restrict__ x,
    const float* __restrict__ gc_b, const float* __restrict__ gamma,
    const float* __restrict__ beta, float* __restrict__ out, ushort* __restrict__ outb){
  int v = blockIdx.x, t = threadIdx.x;
  int m = *flag;
  int s0 = start[v], s1 = start[v+1];
  float dv = dis[v];
  float acc = 0.f;
  for (int ii = s0; ii < s1; ii++){
    int e = bucket[ii];
    int r = m ? ei[2*e] : ei[e];
    float nrm = dv * dis[r];
    acc += nrm * bf2f(xtb[(size_t)r*Dd + t]);
  }
  float val = x[(size_t)v*Dd + t] + acc + gc_b[t];

  float s = val;
  #pragma unroll
  for (int o = 32; o > 0; o >>= 1) s += __shfl_xor(s, o);
  __shared__ float wsum[4], wsum2[4];
  int wid = t >> 6, lane = t & 63;
  if (lane == 0) wsum[wid] = s;
  __syncthreads();
  float mu = (wsum[0]+wsum[1]+wsum[2]+wsum[3]) * (1.0f/Dd);
  float dvl = val - mu;
  float s2 = dvl*dvl;
  #pragma unroll
  for (int o = 32; o > 0; o >>= 1) s2 += __shfl_xor(s2, o);
  if (lane == 0) wsum2[wid] = s2;
  __syncthreads();
  float var = (wsum2[0]+wsum2[1]+wsum2[2]+wsum2[3]) * (1.0f/Dd);
  float res = dvl * rsqrtf(var + 1e-5f) * gamma[t] + beta[t];
  out[(size_t)v*Dd + t] = res;
  outb[(size_t)v*Dd + t] = f2bf(res);
}

__global__ __launch_bounds__(256) void add_ln_kernel(
    const float* __restrict__ a, const float* __restrict__ b,
    const float* __restrict__ gamma, const float* __restrict__ beta,
    float* __restrict__ out, ushort* __restrict__ outb){
  int row = blockIdx.x, t = threadIdx.x;
  size_t off = (size_t)row*Dd + t;
  float val = a[off] + b[off];

  float s = val;
  #pragma unroll
  for (int o = 32; o > 0; o >>= 1) s += __shfl_xor(s, o);
  __shared__ float wsum[4], wsum2[4];
  int wid = t >> 6, lane = t & 63;
  if (lane == 0) wsum[wid] = s;
  __syncthreads();
  float mu = (wsum[0]+wsum[1]+wsum[2]+wsum[3]) * (1.0f/Dd);
  float dvl = val - mu;
  float s2 = dvl*dvl;
  #pragma unroll
  for (int o = 32; o > 0; o >>= 1) s2 += __shfl_xor(s2, o);
  if (lane == 0) wsum2[wid] = s2;
  __syncthreads();
  float var = (wsum2[0]+wsum2[1]+wsum2[2]+wsum2[3]) * (1.0f/Dd);
  float res = dvl * rsqrtf(var + 1e-5f) * gamma[t] + beta[t];
  out[off] = res;
  if (outb) outb[off] = f2bf(res);
}

// ---------------- bf16 MFMA GEMM ----------------
#define LDA_S 56

template<int OB, int ACT>
__global__ __launch_bounds__(256,2) void gemm_bf16(
    const ushort* __restrict__ A, const ushort* __restrict__ Bt,
    const float* __restrict__ bias, float* __restrict__ Cf, ushort* __restrict__ Cb,
    int M, int K, int N, int scale_cols, float scalev){
  __shared__ ushort As[2][128*LDA_S];
  __shared__ ushort Bs[2][64*LDA_S];
  int t = threadIdx.x;
  int lane = t & 63, wid = t >> 6;
  int wm = wid >> 1, wn = wid & 1;
  int l15 = lane & 15, lg = lane >> 4;
  int m0 = blockIdx.y * 128, n0 = blockIdx.x * 64;

  int sr = t >> 2;
  int sk = (t & 3) * 8;
  const ushort* Ag1 = A  + (size_t)(m0 + sr) * K + sk;
  const ushort* Ag2 = A  + (size_t)(m0 + 64 + sr) * K + sk;
  const ushort* Bg  = Bt + (size_t)(n0 + sr) * K + sk;

  int nsteps = K / 32;
  bf8 ra1 = *(const bf8*)Ag1;
  bf8 ra2 = *(const bf8*)Ag2;
  bf8 rb  = *(const bf8*)Bg;
  *(bf8*)&As[0][sr*LDA_S + sk]        = ra1;
  *(bf8*)&As[0][(64+sr)*LDA_S + sk]   = ra2;
  *(bf8*)&Bs[0][sr*LDA_S + sk]        = rb;
  __syncthreads();

  f4 acc[4][2] = {};
  for (int ks = 0; ks < nsteps; ks++){
    int cur = ks & 1;
    if (ks + 1 < nsteps){
      ra1 = *(const bf8*)(Ag1 + (ks+1)*32);
      ra2 = *(const bf8*)(Ag2 + (ks+1)*32);
      rb  = *(const bf8*)(Bg  + (ks+1)*32);
    }
    bf8 af[4], bfr[2];
    #pragma unroll
    for (int mf = 0; mf < 4; mf++)
      af[mf] = *(bf8*)&As[cur][(wm*64 + mf*16 + l15)*LDA_S + lg*8];
    #pragma unroll
    for (int nf = 0; nf < 2; nf++)
      bfr[nf] = *(bf8*)&Bs[cur][(wn*32 + nf*16 + l15)*LDA_S + lg*8];
    #pragma unroll
    for (int mf = 0; mf < 4; mf++)
      #pragma unroll
      for (int nf = 0; nf < 2; nf++)
        acc[mf][nf] = __builtin_amdgcn_mfma_f32_16x16x32_bf16(af[mf], bfr[nf], acc[mf][nf], 0, 0, 0);
    __syncthreads();
    if (ks + 1 < nsteps){
      int nxt = cur ^ 1;
      *(bf8*)&As[nxt][sr*LDA_S + sk]      = ra1;
      *(bf8*)&As[nxt][(64+sr)*LDA_S + sk] = ra2;
      *(bf8*)&Bs[nxt][sr*LDA_S + sk]      = rb;
      __syncthreads();
    }
  }

  #pragma unroll
  for (int mf = 0; mf < 4; mf++){
    int row = m0 + wm*64 + mf*16 + lg*4;
    #pragma unroll
    for (int nf = 0; nf < 2; nf++){
      int col = n0 + wn*32 + nf*16 + l15;
      float bv = bias ? bias[col] : 0.f;
      #pragma unroll
      for (int r = 0; r < 4; r++){
        float v = acc[mf][nf][r] + bv;
        if (col < scale_cols) v *= scalev;
        if (ACT) v = gelu_f(v);
        if (OB) Cb[(size_t)(row + r) * N + col] = f2bf(v);
        else    Cf[(size_t)(row + r) * N + col] = v;
      }
    }
  }
}

// ---------------- MFMA flash attention v2 (swapped QK^T, lane-local softmax) ---
// block: (b,h, 64 q rows); 4 waves x 16 q. Q pre-scaled by 1/sqrt(32) in GEMM.
__global__ __launch_bounds__(256,4) void attn2_kernel(
    const ushort* __restrict__ QKV, const ushort* __restrict__ VtG,
    ushort* __restrict__ AO){
  __shared__ ushort Pl[64 * PS];
  __shared__ ushort Vt[32 * VS];
  int bh = blockIdx.x >> 5, qb = blockIdx.x & 31;
  int b = bh >> 3, h = bh & 7;
  const ushort* Qg = QKV + (size_t)(b*Nn)*SD + h*DHh;
  const ushort* Kg = QKV + (size_t)(b*Nn)*SD + 256 + h*DHh;
  const ushort* VtGh = VtG + (size_t)bh * DHh * Nn;
  int t = threadIdx.x;
  int lane = t & 63, wid = t >> 6;
  int l15 = lane & 15, lg = lane >> 4;
  int q0 = qb*64 + wid*16;

  // Q B-frag: lane holds Q[q0+l15][lg*8..+7]
  bf8 qf = *(const bf8*)&Qg[(size_t)(q0 + l15)*SD + lg*8];

  float m_st = -1e30f, l_st = 0.f;
  f4 oacc[2] = {};
  ushort* Pw = Pl + wid*16*PS;
  int vrow = t >> 3, vslot = t & 7;

  for (int k0 = 0; k0 < Nn; k0 += 64){
    // early global Vt chunk load (written to LDS after barrier1)
    bf8 vreg = *(const bf8*)&VtGh[(size_t)vrow*Nn + k0 + vslot*8];

    // swapped QK^T: D[key][q]; in-lane: 16 scores for q=l15, keys kt*16+lg*4+r
    f4 s[4] = {};
    #pragma unroll
    for (int kt = 0; kt < 4; kt++){
      bf8 kf = *(const bf8*)&Kg[(size_t)(k0 + kt*16 + l15)*SD + lg*8];
      s[kt] = __builtin_amdgcn_mfma_f32_16x16x32_bf16(kf, qf, s[kt], 0, 0, 0);
    }

    float mx = s[0][0];
    #pragma unroll
    for (int kt = 0; kt < 4; kt++)
      #pragma unroll
      for (int r = 0; r < 4; r++)
        mx = fmaxf(mx, s[kt][r]);
    mx = fmaxf(mx, __shfl_xor(mx, 16));
    mx = fmaxf(mx, __shfl_xor(mx, 32));
    float Mn = fmaxf(m_st, mx);
    float corr = __expf(m_st - Mn);
    float ps = 0.f;
    ushort4 pk[4];
    #pragma unroll
    for (int kt = 0; kt < 4; kt++){
      ushort pr[4];
      #pragma unroll
      for (int r = 0; r < 4; r++){
        float p = __expf(s[kt][r] - Mn);
        pr[r] = (ushort)(__float_as_uint(p) >> 16);   // trunc-to-bf16 (p>=0)
        ps += __uint_as_float((unsigned)pr[r] << 16); // consistent with O
      }
      pk[kt].x = pr[0]; pk[kt].y = pr[1]; pk[kt].z = pr[2]; pk[kt].w = pr[3];
    }
    ps += __shfl_xor(ps, 16);
    ps += __shfl_xor(ps, 32);
    l_st = l_st * corr + ps;
    m_st = Mn;
    // rescale O rows (row q = lg*4+r needs corr from lane l15=q)
    #pragma unroll
    for (int r = 0; r < 4; r++){
      float cr = __shfl(corr, (lane & 48) | (((lane >> 4) & 3) * 4 + r));
      oacc[0][r] *= cr;
      oacc[1][r] *= cr;
    }
    // write packed P (4 consecutive keys per 8B store)
    #pragma unroll
    for (int kt = 0; kt < 4; kt++)
      *(ushort4*)&Pw[l15*PS + kt*16 + lg*4] = pk[kt];

    __syncthreads();                    // prev PV reads of Vt done
    *(bf8*)&Vt[vrow*VS + vslot*8] = vreg;
    __syncthreads();                    // Vt staged (P is wave-private, in-order)

    // PV: O[16q x 32dh] += P[16x64] * V^T
    #pragma unroll
    for (int ksb = 0; ksb < 2; ksb++){
      bf8 pf = *(bf8*)&Pw[l15*PS + ksb*32 + lg*8];
      #pragma unroll
      for (int nt = 0; nt < 2; nt++){
        bf8 vf = *(bf8*)&Vt[(nt*16 + l15)*VS + ksb*32 + lg*8];
        oacc[nt] = __builtin_amdgcn_mfma_f32_16x16x32_bf16(pf, vf, oacc[nt], 0, 0, 0);
      }
    }
  }

  float invl = 1.0f / l_st;
  #pragma unroll
  for (int r = 0; r < 4; r++){
    float il = __shfl(invl, (lane & 48) | (((lane >> 4) & 3) * 4 + r));
    int row = b*Nn + q0 + lg*4 + r;
    #pragma unroll
    for (int nt = 0; nt < 2; nt++)
      AO[(size_t)row*Dd + h*DHh + nt*16 + l15] = f2bf(oacc[nt][r] * il);
  }
}

extern "C" void kernel_launch(void* const* d_in, const int* in_sizes, int n_in,
                              void* d_out, int out_size, void* d_ws, size_t ws_size,
                              hipStream_t stream){
  const float* x      = (const float*)d_in[0];
  const int*   ei     = (const int*)d_in[1];
  const float* gc_w   = (const float*)d_in[2];
  const float* gc_b   = (const float*)d_in[3];
  const float* g_gamma= (const float*)d_in[4];
  const float* g_beta = (const float*)d_in[5];
  const float* wq = (const float*)d_in[6];  const float* bq = (const float*)d_in[7];
  const float* wk = (const float*)d_in[8];  const float* bk = (const float*)d_in[9];
  const float* wv = (const float*)d_in[10]; const float* bv = (const float*)d_in[11];
  const float* wo = (const float*)d_in[12]; const float* bo = (const float*)d_in[13];
  const float* a_gamma = (const float*)d_in[14]; const float* a_beta = (const float*)d_in[15];
  const float* w1 = (const float*)d_in[16]; const float* b1 = (const float*)d_in[17];
  const float* w2 = (const float*)d_in[18]; const float* b2 = (const float*)d_in[19];
  const float* m_gamma = (const float*)d_in[20]; const float* m_beta = (const float*)d_in[21];
  float* out = (float*)d_out;

  const size_t S = (size_t)BNr * Dd;   // 2,097,152

  char* p = (char*)d_ws;
  auto alloc = [&](size_t bytes){ char* r = p; p += (bytes + 255) & ~(size_t)255; return r; };

  float* X1    = (float*)alloc(S * 4);
  float* X2    = (float*)alloc(S * 4);
  float* MO    = (float*)alloc(S * 4);
  ushort* QKVb = (ushort*)alloc((size_t)BNr * SD * 2);   // PROJ aliases front
  ushort* regA = (ushort*)alloc(S * 2);   // xbf then AOb
  ushort* regB = (ushort*)alloc(S * 2);   // XTb then X2b
  ushort* X1b  = (ushort*)alloc(S * 2);
  ushort* VtG  = (ushort*)alloc(S * 2);
  ushort* Hb   = (ushort*)alloc((size_t)BNr * MLPH * 2);
  ushort* gcwT = (ushort*)alloc(65536 * 2);
  ushort* wqkvT= (ushort*)alloc((size_t)SD * 256 * 2);
  ushort* woT  = (ushort*)alloc(65536 * 2);
  ushort* w1T  = (ushort*)alloc(262144 * 2);
  ushort* w2T  = (ushort*)alloc(262144 * 2);
  float* bqkv  = (float*)alloc(SD * 4);
  int* cnt_row = (int*)alloc(8192 * 4);
  int* cnt_col = (int*)alloc(8192 * 4);
  int* startA  = (int*)alloc(8200 * 4);
  int* cursor  = (int*)alloc(8192 * 4);
  int* bucket  = (int*)alloc(Ee * 4);
  float* dis   = (float*)alloc(8192 * 4);
  int* flag    = (int*)alloc(256);

  ushort* xbf = regA;  ushort* AOb = regA;
  ushort* XTb = regB;  ushort* X2b = regB;
  float*  PROJ = (float*)QKVb;

  hipMemsetAsync(cnt_row, 0, 8192 * sizeof(int), stream);
  hipMemsetAsync(cnt_col, 0, 8192 * sizeof(int), stream);

  // graph prep
  detect_kernel<<<1, 256, 0, stream>>>(ei, flag);
  count_kernel<<<Ee/256, 256, 0, stream>>>(ei, flag, cnt_row, cnt_col);
  scan_kernel<<<1, 256, 0, stream>>>(cnt_col, startA, cursor);
  dis_kernel<<<32, 256, 0, stream>>>(cnt_row, dis);
  fill_kernel<<<Ee/256, 256, 0, stream>>>(ei, flag, cursor, bucket);

  // converts
  conv_kernel<<<(int)(S/4/256), 256, 0, stream>>>(x, xbf, (int)(S/4));
  tconv5_kernel<<<dim3(8,8,5), 256, 0, stream>>>(gc_w, wq, wk, wv, wo,
      gcwT, wqkvT, wqkvT + 65536, wqkvT + 131072, woT);
  tconv_kernel<<<dim3(32,8), 256, 0, stream>>>(w1, w1T, 256, 1024);
  tconv_kernel<<<dim3(8,32), 256, 0, stream>>>(w2, w2T, 1024, 256);
  bias_cat_kernel<<<3, 256, 0, stream>>>(bq, bk, bv, bqkv);

  const float qscale = 0.17677669529663687f;   // 1/sqrt(32)

  // xt = x @ gc_w  (bf16 out)
  gemm_bf16<1,0><<<dim3(Dd/64, BNr/128), 256, 0, stream>>>(
      xbf, gcwT, nullptr, nullptr, XTb, BNr, Dd, Dd, 0, 1.0f);
  // GraphConv gather + residual + LN1
  gather_ln_kernel<<<BNr, 256, 0, stream>>>(XTb, ei, flag, startA, bucket, dis,
                                            x, gc_b, g_gamma, g_beta, X1, X1b);
  // fused QKV (Q pre-scaled)
  gemm_bf16<1,0><<<dim3(SD/64, BNr/128), 256, 0, stream>>>(
      X1b, wqkvT, bqkv, nullptr, QKVb, BNr, Dd, SD, 256, qscale);
  // V transpose to [bh][dh][n]
  vt_kernel<<<dim3(Nn/32, Bb*Hh), 256, 0, stream>>>(QKVb, VtG);
  // attention
  attn2_kernel<<<Bb*Hh*32, 256, 0, stream>>>(QKVb, VtG, AOb);
  // out proj (fp32, aliases QKVb) + LN2
  gemm_bf16<0,0><<<dim3(Dd/64, BNr/128), 256, 0, stream>>>(
      AOb, woT, bo, PROJ, nullptr, BNr, Dd, Dd, 0, 1.0f);
  add_ln_kernel<<<BNr, 256, 0, stream>>>(X1, PROJ, a_gamma, a_beta, X2, X2b);
  // MLP
  gemm_bf16<1,1><<<dim3(MLPH/64, BNr/128), 256, 0, stream>>>(
      X2b, w1T, b1, nullptr, Hb, BNr, Dd, MLPH, 0, 1.0f);
  gemm_bf16<0,0><<<dim3(Dd/64, BNr/128), 256, 0, stream>>>(
      Hb, w2T, b2, MO, nullptr, BNr, MLPH, Dd, 0, 1.0f);
  add_ln_kernel<<<BNr, 256, 0, stream>>>(X2, MO, m_gamma, m_beta, out, nullptr);
}